// Round 13
// baseline (282.632 us; speedup 1.0000x reference)
//
#include <hip/hip_runtime.h>
#include <hip/hip_bf16.h>

typedef __hip_bfloat16 bf16;

#define R_NUM 40000
#define E_NUM 500000

// wbuf layout (f32 element offsets)
#define W_P1W 0
#define W_P1B 4096
#define W_APW 4160    // 2*128*64
#define W_APB 20544   // 2*64
#define W_ABIN 20672  // 2*10*8
#define W_AVEC 20832  // 2*8*8
#define W_AW 20960    // 2*64*64
#define W_AB 29152
#define W_RW 29280
#define W_RB 37472
#define W_END 37600
#define WCONV_BLOCKS 147  // ceil(W_END/256)
#define SCAT_BLOCKS 1954  // ceil(E/256)
#define EMB_BLOCKS 1250   // R/32

// ws byte offsets
#define O_FLAG 0
#define O_WBUF 256
#define O_ROWP 150784
#define O_CNTS 310784
#define O_PART 470784
#define O_STB 471040
#define O_BIG 2471296  // stb + 64-int zero pad
#define XMP_BYTES 10240000ull   // R*64 u32
#define HR_BYTES 20480000ull    // R*64 float2
#define XM32_BYTES 20480000ull  // R*64 float2 (fallback)
#define NEED_LEAN (O_BIG + XMP_BYTES + HR_BYTES)
#define NEED_XM1 (O_BIG + XM32_BYTES)

static __device__ __forceinline__ float b2f(bf16 x) { return __bfloat162float(x); }
static __device__ __forceinline__ float ldv(const float* p, size_t i) { return p[i]; }
static __device__ __forceinline__ float ldv(const bf16* p, size_t i) { return __bfloat162float(p[i]); }
static __device__ __forceinline__ void stv(float* p, size_t i, float v) { p[i] = v; }
static __device__ __forceinline__ void stv(bf16* p, size_t i, float v) { p[i] = __float2bfloat16(v); }

// round-to-nearest-even f32 -> bf16 bits
static __device__ __forceinline__ unsigned int f2bb(float x) {
  union { float f; unsigned int u; } v;
  v.f = x;
  unsigned int r = v.u + 0x7FFFu + ((v.u >> 16) & 1u);
  return r >> 16;
}
static __device__ __forceinline__ unsigned int packxm(float xt, float mt) {
  return f2bb(xt) | (f2bb(mt) << 16);
}

// ---------------- detect + zero-init (fused) ----------------

__global__ void k_detect_init(const unsigned int* __restrict__ trip_w,
                              const unsigned short* __restrict__ emb_w, int* __restrict__ flag,
                              int* __restrict__ counts, int* __restrict__ stb,
                              int* __restrict__ partial) {
  int tid = threadIdx.x;
  if (blockIdx.x == 0) {
    if (tid < 64) {
      int lane = tid;
      unsigned int acc = 0;
      for (int i = lane; i < 1024; i += 64) acc |= trip_w[2 * i + 1];
      int votes = 0;
      for (int i = lane; i < 2048; i += 64) {
        unsigned short u = emb_w[2 * i];
        int ex = (u >> 7) & 0xFF;
        if (ex >= 90 && ex <= 130) votes++;
      }
      for (int off = 1; off < 64; off <<= 1) {
        acc |= __shfl_xor(acc, off);
        votes += __shfl_xor(votes, off);
      }
      if (lane == 0) {
        flag[0] = (acc == 0) ? 1 : 0;
        flag[1] = (votes < 1024) ? 1 : 0;
      }
    }
    return;
  }
  int g = (blockIdx.x - 1) * 256 + tid;
  for (int i = g; i < R_NUM; i += 159 * 256) counts[i] = 0;
  if (blockIdx.x == 1 && tid < 64) {
    stb[E_NUM + tid] = 0;   // window over-read pad
    partial[tid] = -1;      // lookback-scan sentinel
  }
}

// ---------------- hist + wconv (fused) ----------------

static __device__ __forceinline__ void load_edge(const unsigned int* __restrict__ w, int e,
                                                 int i64, int& h, int& t, int& b) {
  if (i64) {
    h = (int)w[6 * e + 0];
    t = (int)w[6 * e + 2];
    b = (int)w[6 * e + 4];
  } else {
    h = (int)w[3 * e + 0];
    t = (int)w[3 * e + 1];
    b = (int)w[3 * e + 2];
  }
}

__global__ void k_hist_wconv(const unsigned int* __restrict__ trip_w, const int* __restrict__ flag,
                             int* __restrict__ counts, const void* p1w, const void* p1b,
                             const void* apw, const void* apb, const void* abin, const void* avec,
                             const void* aw, const void* ab, const void* rw, const void* rb,
                             float* __restrict__ wbuf) {
  if (blockIdx.x < WCONV_BLOCKS) {
    int i = blockIdx.x * 256 + threadIdx.x;
    if (i >= W_END) return;
    const void* src;
    int off;
    if (i < W_P1B) { src = p1w; off = i - W_P1W; }
    else if (i < W_APW) { src = p1b; off = i - W_P1B; }
    else if (i < W_APB) { src = apw; off = i - W_APW; }
    else if (i < W_ABIN) { src = apb; off = i - W_APB; }
    else if (i < W_AVEC) { src = abin; off = i - W_ABIN; }
    else if (i < W_AW) { src = avec; off = i - W_AVEC; }
    else if (i < W_AB) { src = aw; off = i - W_AW; }
    else if (i < W_RW) { src = ab; off = i - W_AB; }
    else if (i < W_RB) { src = rw; off = i - W_RW; }
    else { src = rb; off = i - W_RB; }
    wbuf[i] = flag[1] ? ((const float*)src)[off] : b2f(((const bf16*)src)[off]);
    return;
  }
  int e = (blockIdx.x - WCONV_BLOCKS) * 256 + threadIdx.x;
  if (e >= E_NUM) return;
  int h, t, b;
  load_edge(trip_w, e, flag[0], h, t, b);
  atomicAdd(&counts[h], 1);
}

// ---------------- single-dispatch lookback scan ----------------
// 40 blocks (all co-resident on 256 CUs). Publish own total BEFORE spinning
// on predecessors -> deadlock-free. Device-scope atomics (cross-XCD safe).

__global__ void k_scan1(const int* __restrict__ counts, int* __restrict__ partial,
                        int* __restrict__ row_ptr) {
  __shared__ int sd[1024];
  __shared__ int soff;
  int tid = threadIdx.x;
  int b = blockIdx.x;
  int idx = b * 1024 + tid;
  int v = (idx < R_NUM) ? counts[idx] : 0;
  sd[tid] = v;
  __syncthreads();
  for (int off = 1; off < 1024; off <<= 1) {
    int t = (tid >= off) ? sd[tid - off] : 0;
    __syncthreads();
    sd[tid] += t;
    __syncthreads();
  }
  if (tid == 0) {
    atomicExch(&partial[b], sd[1023]);  // publish (counts are >= 0)
    int s = 0;
    for (int i = 0; i < b; i++) {
      int p;
      do { p = atomicAdd(&partial[i], 0); } while (p == -1);
      s += p;
    }
    soff = s;
  }
  __syncthreads();
  if (idx < R_NUM) row_ptr[idx] = soff + sd[tid] - v;  // exclusive
}

// ---------------- fused scatter + emb0 + packed XM(l0) + HR(l0) ----------------
// Blocks [0, SCAT_BLOCKS): counting-sort scatter (bumps row_ptr; afterwards
// row_ptr[r] == end(r), beg(r) = r ? row_ptr[r-1] : 0).
// Blocks [SCAT_BLOCKS, +EMB_BLOCKS): emb0 + layer-0 XMp/HR, 8 rows/thread,
// float4 LDS reads + 4 fused weight streams (DS-instruction diet).

__global__ void __launch_bounds__(256, 4) k_scat_emb(
    const unsigned int* __restrict__ trip_w, const int* __restrict__ flag,
    int* __restrict__ row_ptr, int* __restrict__ stb, const void* __restrict__ A,
    const float* __restrict__ wbuf, float* __restrict__ emb, unsigned int* __restrict__ XMp,
    float2* __restrict__ HR) {
  if (blockIdx.x < SCAT_BLOCKS) {
    int e = blockIdx.x * 256 + threadIdx.x;
    if (e >= E_NUM) return;
    int h, t, b;
    load_edge(trip_w, e, flag[0], h, t, b);
    int pos = atomicAdd(&row_ptr[h], 1);
    stb[pos] = (t & 0xFFFF) | (b << 16);
    return;
  }
  int bid = blockIdx.x - SCAT_BLOCKS;
  int j = threadIdx.x & 63;
  int g = threadIdx.x >> 6;
  int r0 = bid * 32 + g * 8;
  int f32 = flag[1];
  __shared__ float sA[32][64];
  for (int k = threadIdx.x; k < 2048; k += 256) {
    int rr = k >> 6, cc = k & 63;
    size_t idx = (size_t)(bid * 32 + rr) * 64 + cc;
    sA[rr][cc] = f32 ? ((const float*)A)[idx] : b2f(((const bf16*)A)[idx]);
  }
  __syncthreads();
  int base = g * 8;
  float a[8] = {0.f, 0.f, 0.f, 0.f, 0.f, 0.f, 0.f, 0.f};
  {
    const float* W = wbuf + W_P1W;
    for (int i4 = 0; i4 < 64; i4 += 4) {
      float4 ev[8];
#pragma unroll
      for (int n = 0; n < 8; n++) ev[n] = *(const float4*)&sA[base + n][i4];
#pragma unroll
      for (int di = 0; di < 4; di++) {
        float w = W[(i4 + di) * 64 + j];
#pragma unroll
        for (int n = 0; n < 8; n++)
          a[n] = fmaf(((const float*)&ev[n])[di], w, a[n]);
      }
    }
    float bj = wbuf[W_P1B + j];
#pragma unroll
    for (int n = 0; n < 8; n++) {
      a[n] = fmaxf(a[n] + bj, 0.f);
      emb[(size_t)(r0 + n) * 64 + j] = a[n];
    }
  }
  __syncthreads();
#pragma unroll
  for (int n = 0; n < 8; n++) sA[base + n][j] = a[n];
  __syncthreads();
  {
    const float* pwb = wbuf + W_APW + 4096;
    const float* aw = wbuf + W_AW;
    const float* pwt = wbuf + W_APW;
    const float* rw = wbuf + W_RW;
    float axt[8] = {0.f, 0.f, 0.f, 0.f, 0.f, 0.f, 0.f, 0.f};
    float amt[8] = {0.f, 0.f, 0.f, 0.f, 0.f, 0.f, 0.f, 0.f};
    float axh[8] = {0.f, 0.f, 0.f, 0.f, 0.f, 0.f, 0.f, 0.f};
    float ars[8] = {0.f, 0.f, 0.f, 0.f, 0.f, 0.f, 0.f, 0.f};
    for (int i4 = 0; i4 < 64; i4 += 4) {
      float4 ev[8];
#pragma unroll
      for (int n = 0; n < 8; n++) ev[n] = *(const float4*)&sA[base + n][i4];
#pragma unroll
      for (int di = 0; di < 4; di++) {
        int i = i4 + di;
        float wt = pwb[i * 64 + j];
        float wm = aw[i * 64 + j];
        float wh = pwt[i * 64 + j];
        float wr = rw[i * 64 + j];
#pragma unroll
        for (int n = 0; n < 8; n++) {
          float e = ((const float*)&ev[n])[di];
          axt[n] = fmaf(e, wt, axt[n]);
          amt[n] = fmaf(e, wm, amt[n]);
          axh[n] = fmaf(e, wh, axh[n]);
          ars[n] = fmaf(e, wr, ars[n]);
        }
      }
    }
    float abj = wbuf[W_AB + j];
    float pbj = wbuf[W_APB + j];
    float rbj = wbuf[W_RB + j];
#pragma unroll
    for (int n = 0; n < 8; n++) {
      XMp[(size_t)(r0 + n) * 64 + j] = packxm(axt[n], amt[n] + abj);
      HR[(size_t)(r0 + n) * 64 + j] = make_float2(axh[n] + pbj, fmaxf(ars[n] + rbj, 0.f));
    }
  }
}

// ---------------- node-parallel packed XM+HR, layer l; 4 fused streams ----------------

__global__ void __launch_bounds__(256, 4) k_xmhr_p(const float* __restrict__ emb,
                                                   const float* __restrict__ wbuf, int l,
                                                   unsigned int* __restrict__ XMp,
                                                   float2* __restrict__ HR) {
  int j = threadIdx.x & 63;
  int g = threadIdx.x >> 6;
  int r0 = blockIdx.x * 32 + g * 8;
  __shared__ float sE[32][64];
  for (int k = threadIdx.x; k < 2048; k += 256) {
    int rr = k >> 6, cc = k & 63;
    sE[rr][cc] = emb[(size_t)(blockIdx.x * 32 + rr) * 64 + cc];
  }
  __syncthreads();
  int base = g * 8;
  const float* pwb = wbuf + W_APW + l * 8192 + 4096;
  const float* aw = wbuf + W_AW + l * 4096;
  const float* pwt = wbuf + W_APW + l * 8192;
  const float* rw = wbuf + W_RW + l * 4096;
  float axt[8] = {0.f, 0.f, 0.f, 0.f, 0.f, 0.f, 0.f, 0.f};
  float amt[8] = {0.f, 0.f, 0.f, 0.f, 0.f, 0.f, 0.f, 0.f};
  float axh[8] = {0.f, 0.f, 0.f, 0.f, 0.f, 0.f, 0.f, 0.f};
  float ars[8] = {0.f, 0.f, 0.f, 0.f, 0.f, 0.f, 0.f, 0.f};
  for (int i4 = 0; i4 < 64; i4 += 4) {
    float4 ev[8];
#pragma unroll
    for (int n = 0; n < 8; n++) ev[n] = *(const float4*)&sE[base + n][i4];
#pragma unroll
    for (int di = 0; di < 4; di++) {
      int i = i4 + di;
      float wt = pwb[i * 64 + j];
      float wm = aw[i * 64 + j];
      float wh = pwt[i * 64 + j];
      float wr = rw[i * 64 + j];
#pragma unroll
      for (int n = 0; n < 8; n++) {
        float e = ((const float*)&ev[n])[di];
        axt[n] = fmaf(e, wt, axt[n]);
        amt[n] = fmaf(e, wm, amt[n]);
        axh[n] = fmaf(e, wh, axh[n]);
        ars[n] = fmaf(e, wr, ars[n]);
      }
    }
  }
  float abj = wbuf[W_AB + l * 64 + j];
  float pbj = wbuf[W_APB + l * 64 + j];
  float rbj = wbuf[W_RB + l * 64 + j];
#pragma unroll
  for (int n = 0; n < 8; n++) {
    XMp[(size_t)(r0 + n) * 64 + j] = packxm(axt[n], amt[n] + abj);
    HR[(size_t)(r0 + n) * 64 + j] = make_float2(axh[n] + pbj, fmaxf(ars[n] + rbj, 0.f));
  }
}

// ---------------- 2-row edge kernel: 32 gathers in flight ----------------

static __device__ __forceinline__ void consume16(const int* pk, const unsigned int* xp, float xh,
                                                 float av, const float* sab, int hh, int j0,
                                                 int end, float& num, float& den) {
#pragma unroll
  for (int k = 0; k < 16; k++) {
    float xt = __uint_as_float(xp[k] << 16);
    float mt = __uint_as_float(xp[k] & 0xFFFF0000u);
    float z = xh + xt;
    z = (z > 0.f) ? z : 0.2f * z;
    float v = z * av;
    v += __shfl_xor(v, 1);
    v += __shfl_xor(v, 2);
    v += __shfl_xor(v, 4);
    float e = __expf(v + sab[(pk[k] >> 16) * 8 + hh]);
    e = (j0 + k < end) ? e : 0.f;
    den += e;
    num = fmaf(mt, e, num);
  }
}

static __device__ __forceinline__ void edge_window(const int* __restrict__ stb,
                                                   const unsigned int* __restrict__ XMp, int j,
                                                   int end, int lane, int hh, float xh, float av,
                                                   const float* sab, float& num, float& den) {
  int pk[16];
  unsigned int xp[16];
#pragma unroll
  for (int k = 0; k < 16; k++) pk[k] = stb[j + k];
#pragma unroll
  for (int k = 0; k < 16; k++) xp[k] = XMp[(size_t)(pk[k] & 0xFFFF) * 64 + lane];
  consume16(pk, xp, xh, av, sab, hh, j, end, num, den);
}

__global__ void __launch_bounds__(256, 4) k_edge_lean(
    const int* __restrict__ row_ptr, const int* __restrict__ stb,
    const unsigned int* __restrict__ XMp, const float2* __restrict__ HR,
    const float* __restrict__ wbuf, int l, float* __restrict__ emb) {
  __shared__ float sab[80];
  int tid = threadIdx.x;
  int lane = tid & 63;
  int w = tid >> 6;
  int hh = lane >> 3;
  if (tid < 80) {
    float a = wbuf[W_ABIN + l * 80 + tid];
    sab[tid] = (a > 0.f) ? a : 0.2f * a;
  }
  __syncthreads();
  float av = wbuf[W_AVEC + l * 64 + lane];

  int r = blockIdx.x * 8 + w * 2;  // rows r, r+1 (contiguous in stb)
  float2 hrA = HR[(size_t)r * 64 + lane];
  float2 hrB = HR[(size_t)(r + 1) * 64 + lane];
  int begA = (r == 0) ? 0 : row_ptr[r - 1];
  int endA = row_ptr[r];
  int endB = row_ptr[r + 1];
  begA = __builtin_amdgcn_readfirstlane(begA);
  endA = __builtin_amdgcn_readfirstlane(endA);
  endB = __builtin_amdgcn_readfirstlane(endB);
  int begB = endA;

  float numA = 0.f, denA = 0.f, numB = 0.f, denB = 0.f;
  {  // combined first super-window: 32 gathers issued before any consume
    int pkA[16], pkB[16];
    unsigned int xpA[16], xpB[16];
#pragma unroll
    for (int k = 0; k < 16; k++) pkA[k] = stb[begA + k];
#pragma unroll
    for (int k = 0; k < 16; k++) pkB[k] = stb[begB + k];
#pragma unroll
    for (int k = 0; k < 16; k++) xpA[k] = XMp[(size_t)(pkA[k] & 0xFFFF) * 64 + lane];
#pragma unroll
    for (int k = 0; k < 16; k++) xpB[k] = XMp[(size_t)(pkB[k] & 0xFFFF) * 64 + lane];
    consume16(pkA, xpA, hrA.x, av, sab, hh, begA, endA, numA, denA);
    consume16(pkB, xpB, hrB.x, av, sab, hh, begB, endB, numB, denB);
  }
  for (int j = begA + 16; j < endA; j += 16)
    edge_window(stb, XMp, j, endA, lane, hh, hrA.x, av, sab, numA, denA);
  for (int j = begB + 16; j < endB; j += 16)
    edge_window(stb, XMp, j, endB, lane, hh, hrB.x, av, sab, numB, denB);

  emb[(size_t)r * 64 + lane] = fmaxf(numA / (denA + 1e-16f), 0.f) + hrA.y;
  emb[(size_t)(r + 1) * 64 + lane] = fmaxf(numB / (denB + 1e-16f), 0.f) + hrB.y;
}

// ---------------- fallback kernels (XM1 / Plan D paths) ----------------

__global__ void k_scatter(const unsigned int* __restrict__ trip_w, const int* __restrict__ flag,
                          int* __restrict__ row_ptr, int* __restrict__ stb) {
  int e = blockIdx.x * 256 + threadIdx.x;
  if (e >= E_NUM) return;
  int h, t, b;
  load_edge(trip_w, e, flag[0], h, t, b);
  int pos = atomicAdd(&row_ptr[h], 1);
  stb[pos] = (t & 0xFFFF) | (b << 16);
}

__global__ void k_emb0(const void* __restrict__ A, const int* __restrict__ flag,
                       const float* __restrict__ wbuf, float* __restrict__ emb) {
  int j = threadIdx.x & 63;
  int g = threadIdx.x >> 6;
  int r0 = blockIdx.x * 16 + g * 4;
  int f32 = flag[1];
  __shared__ float sA[16][64];
  for (int k = threadIdx.x; k < 1024; k += 256) {
    int rr = k >> 6, cc = k & 63;
    size_t idx = (size_t)(blockIdx.x * 16 + rr) * 64 + cc;
    sA[rr][cc] = f32 ? ((const float*)A)[idx] : b2f(((const bf16*)A)[idx]);
  }
  __syncthreads();
  const float* W = wbuf + W_P1W;
  float a[4] = {0.f, 0.f, 0.f, 0.f};
  int base = g * 4;
  for (int i = 0; i < 64; i++) {
    float w = W[i * 64 + j];
#pragma unroll
    for (int n = 0; n < 4; n++) a[n] = fmaf(sA[base + n][i], w, a[n]);
  }
  float bj = wbuf[W_P1B + j];
#pragma unroll
  for (int n = 0; n < 4; n++)
    emb[(size_t)(r0 + n) * 64 + j] = fmaxf(a[n] + bj, 0.f);
}

__global__ void k_xm(const float* __restrict__ emb, const float* __restrict__ wbuf, int l,
                     float2* __restrict__ XM) {
  int j = threadIdx.x & 63;
  int g = threadIdx.x >> 6;
  int r0 = blockIdx.x * 16 + g * 4;
  __shared__ float sE[16][64];
  for (int k = threadIdx.x; k < 1024; k += 256) {
    int rr = k >> 6, cc = k & 63;
    sE[rr][cc] = emb[(size_t)(blockIdx.x * 16 + rr) * 64 + cc];
  }
  __syncthreads();
  const float* pwb = wbuf + W_APW + l * 8192 + 4096;
  const float* aw = wbuf + W_AW + l * 4096;
  float axt[4] = {0.f, 0.f, 0.f, 0.f};
  float amt[4] = {0.f, 0.f, 0.f, 0.f};
  int base = g * 4;
  for (int i = 0; i < 64; i++) {
    float wt = pwb[i * 64 + j];
    float wm = aw[i * 64 + j];
#pragma unroll
    for (int n = 0; n < 4; n++) {
      float e = sE[base + n][i];
      axt[n] = fmaf(e, wt, axt[n]);
      amt[n] = fmaf(e, wm, amt[n]);
    }
  }
  float abj = wbuf[W_AB + l * 64 + j];
#pragma unroll
  for (int n = 0; n < 4; n++)
    XM[(size_t)(r0 + n) * 64 + j] = make_float2(axt[n], amt[n] + abj);
}

__global__ void __launch_bounds__(256, 4) k_edge_f(
    const int* __restrict__ row_ptr, const int* __restrict__ stb, const float2* __restrict__ XM,
    const float* __restrict__ wbuf, int l, float* __restrict__ emb) {
  __shared__ float sab[80];
  int tid = threadIdx.x;
  int lane = tid & 63;
  int w = tid >> 6;
  int hh = lane >> 3;
  if (tid < 80) {
    float a = wbuf[W_ABIN + l * 80 + tid];
    sab[tid] = (a > 0.f) ? a : 0.2f * a;
  }
  __syncthreads();

  const float* pwt = wbuf + W_APW + l * 8192;
  const float* rwp = wbuf + W_RW + l * 4096;
  float av = wbuf[W_AVEC + l * 64 + lane];
  float xh0 = wbuf[W_APB + l * 64 + lane];
  float res0 = wbuf[W_RB + l * 64 + lane];

  int r0 = blockIdx.x * 16 + w * 4;
  for (int rr = 0; rr < 4; rr++) {
    int r = r0 + rr;
    float ev = emb[(size_t)r * 64 + lane];
    float xh = xh0, res = res0;
#pragma unroll 16
    for (int i = 0; i < 64; i++) {
      float e = __shfl(ev, i);
      xh = fmaf(e, pwt[i * 64 + lane], xh);
      res = fmaf(e, rwp[i * 64 + lane], res);
    }
    res = fmaxf(res, 0.f);

    int beg = (r == 0) ? 0 : row_ptr[r - 1];
    int end = row_ptr[r];
    beg = __builtin_amdgcn_readfirstlane(beg);
    end = __builtin_amdgcn_readfirstlane(end);

    float num = 0.f, den = 0.f;
    for (int j = beg; j < end; j += 16) {
      int pk[16];
      float2 xmv[16];
#pragma unroll
      for (int k = 0; k < 16; k++) pk[k] = stb[j + k];
#pragma unroll
      for (int k = 0; k < 16; k++) xmv[k] = XM[(size_t)(pk[k] & 0xFFFF) * 64 + lane];
#pragma unroll
      for (int k = 0; k < 16; k++) {
        float z = xh + xmv[k].x;
        z = (z > 0.f) ? z : 0.2f * z;
        float v = z * av;
        v += __shfl_xor(v, 1);
        v += __shfl_xor(v, 2);
        v += __shfl_xor(v, 4);
        float e = __expf(v + sab[(pk[k] >> 16) * 8 + hh]);
        e = (j + k < end) ? e : 0.f;
        den += e;
        num = fmaf(xmv[k].y, e, num);
      }
    }
    emb[(size_t)r * 64 + lane] = fmaxf(num / (den + 1e-16f), 0.f) + res;
  }
}

static __device__ __forceinline__ float dotcol(const float* __restrict__ Wm, float val, int lane) {
  float acc = 0.f;
  for (int i = 0; i < 64; i++) acc = fmaf(__shfl(val, i), Wm[i * 64 + lane], acc);
  return acc;
}

template <typename TIN, typename TOUT>
__global__ void k_edge_d(const int* __restrict__ row_ptr, const int* __restrict__ stb,
                         const float* __restrict__ wbuf, int l, const TIN* __restrict__ emb_in,
                         TOUT* __restrict__ emb_out) {
  __shared__ float sab[80];
  int tid = threadIdx.x;
  int lane = tid & 63;
  int w = tid >> 6;
  int r = blockIdx.x * 4 + w;
  int hh = lane >> 3;
  if (tid < 80) {
    float a = wbuf[W_ABIN + l * 80 + tid];
    sab[tid] = (a > 0.f) ? a : 0.2f * a;
  }
  __syncthreads();
  const float* pwt = wbuf + W_APW + l * 8192;
  const float* pwb = pwt + 4096;
  const float* aw = wbuf + W_AW + l * 4096;
  const float* rw = wbuf + W_RW + l * 4096;

  float ev = ldv(emb_in, (size_t)r * 64 + lane);
  float xh = wbuf[W_APB + l * 64 + lane];
  float res = wbuf[W_RB + l * 64 + lane];
  for (int i = 0; i < 64; i++) {
    float e = __shfl(ev, i);
    xh = fmaf(e, pwt[i * 64 + lane], xh);
    res = fmaf(e, rw[i * 64 + lane], res);
  }
  res = fmaxf(res, 0.f);
  float av = wbuf[W_AVEC + l * 64 + lane];
  float abl = wbuf[W_AB + l * 64 + lane];

  int beg = (r == 0) ? 0 : row_ptr[r - 1];
  int end = row_ptr[r];
  float num = 0.f, den = 0.f;
  for (int j = beg; j < end; j++) {
    int p = stb[j];
    int t = p & 0xFFFF;
    float tv = ldv(emb_in, (size_t)t * 64 + lane);
    float z = xh + dotcol(pwb, tv, lane);
    z = (z > 0.f) ? z : 0.2f * z;
    float v = z * av;
    v += __shfl_xor(v, 1);
    v += __shfl_xor(v, 2);
    v += __shfl_xor(v, 4);
    float e = __expf(v + sab[(p >> 16) * 8 + hh]);
    den += e;
    float mt = dotcol(aw, tv, lane) + abl;
    num = fmaf(mt, e, num);
  }
  stv(emb_out, (size_t)r * 64 + lane, fmaxf(num / (den + 1e-16f), 0.f) + res);
}

// ---------------- launch ----------------

extern "C" void kernel_launch(void* const* d_in, const int* in_sizes, int n_in,
                              void* d_out, int out_size, void* d_ws, size_t ws_size,
                              hipStream_t stream) {
  const unsigned int* trip_w = (const unsigned int*)d_in[0];
  const void* rel_emb = d_in[1];
  float* emb = (float*)d_out;

  char* ws = (char*)d_ws;
  int* flag = (int*)(ws + O_FLAG);
  float* wbuf = (float*)(ws + O_WBUF);
  int* row_ptr = (int*)(ws + O_ROWP);
  int* counts = (int*)(ws + O_CNTS);
  int* partial = (int*)(ws + O_PART);
  int* stb = (int*)(ws + O_STB);
  char* big = ws + O_BIG;

  k_detect_init<<<160, 256, 0, stream>>>(trip_w, (const unsigned short*)rel_emb, flag, counts,
                                         stb, partial);
  int eb_blocks = (E_NUM + 255) / 256;
  k_hist_wconv<<<WCONV_BLOCKS + eb_blocks, 256, 0, stream>>>(
      trip_w, flag, counts, d_in[2], d_in[3], d_in[4], d_in[5], d_in[6], d_in[7], d_in[8],
      d_in[9], d_in[10], d_in[11], wbuf);
  k_scan1<<<40, 1024, 0, stream>>>(counts, partial, row_ptr);

  if (ws_size >= NEED_LEAN) {
    unsigned int* XMp = (unsigned int*)big;
    float2* HR = (float2*)(big + XMP_BYTES);
    k_scat_emb<<<SCAT_BLOCKS + EMB_BLOCKS, 256, 0, stream>>>(trip_w, flag, row_ptr, stb, rel_emb,
                                                             wbuf, emb, XMp, HR);
    k_edge_lean<<<R_NUM / 8, 256, 0, stream>>>(row_ptr, stb, XMp, HR, wbuf, 0, emb);
    k_xmhr_p<<<R_NUM / 32, 256, 0, stream>>>(emb, wbuf, 1, XMp, HR);
    k_edge_lean<<<R_NUM / 8, 256, 0, stream>>>(row_ptr, stb, XMp, HR, wbuf, 1, emb);
  } else if (ws_size >= NEED_XM1) {
    float2* XM = (float2*)big;
    k_scatter<<<eb_blocks, 256, 0, stream>>>(trip_w, flag, row_ptr, stb);
    k_emb0<<<R_NUM / 16, 256, 0, stream>>>(rel_emb, flag, wbuf, emb);
    k_xm<<<R_NUM / 16, 256, 0, stream>>>(emb, wbuf, 0, XM);
    k_edge_f<<<R_NUM / 16, 256, 0, stream>>>(row_ptr, stb, XM, wbuf, 0, emb);
    k_xm<<<R_NUM / 16, 256, 0, stream>>>(emb, wbuf, 1, XM);
    k_edge_f<<<R_NUM / 16, 256, 0, stream>>>(row_ptr, stb, XM, wbuf, 1, emb);
  } else {
    k_scatter<<<eb_blocks, 256, 0, stream>>>(trip_w, flag, row_ptr, stb);
    k_emb0<<<R_NUM / 16, 256, 0, stream>>>(rel_emb, flag, wbuf, emb);
    bf16* embB = (bf16*)big;
    k_edge_d<float, bf16><<<R_NUM / 4, 256, 0, stream>>>(row_ptr, stb, wbuf, 0, emb, embB);
    k_edge_d<bf16, float><<<R_NUM / 4, 256, 0, stream>>>(row_ptr, stb, wbuf, 1, embB, emb);
  }
}

// Round 14
// 280.555 us; speedup vs baseline: 1.0074x; 1.0074x over previous
//
#include <hip/hip_runtime.h>
#include <hip/hip_bf16.h>

typedef __hip_bfloat16 bf16;

#define R_NUM 40000
#define E_NUM 500000

// wbuf layout (f32 element offsets)
#define W_P1W 0
#define W_P1B 4096
#define W_APW 4160    // 2*128*64
#define W_APB 20544   // 2*64
#define W_ABIN 20672  // 2*10*8
#define W_AVEC 20832  // 2*8*8
#define W_AW 20960    // 2*64*64
#define W_AB 29152
#define W_RW 29280
#define W_RB 37472
#define W_END 37600
#define WCONV_BLOCKS 147  // ceil(W_END/256)

// ws byte offsets
#define O_FLAG 0
#define O_WBUF 256
#define O_ROWP 150784
#define O_CNTS 310784
#define O_PART 470784
#define O_STB 471040
#define O_BIG 2471296  // stb + 64-int zero pad
#define XMP_BYTES 10240000ull   // R*64 u32
#define HR_BYTES 20480000ull    // R*64 float2
#define XM32_BYTES 20480000ull  // R*64 float2 (fallback)
#define NEED_LEAN (O_BIG + XMP_BYTES + HR_BYTES)
#define NEED_XM1 (O_BIG + XM32_BYTES)

static __device__ __forceinline__ float b2f(bf16 x) { return __bfloat162float(x); }
static __device__ __forceinline__ float ldv(const float* p, size_t i) { return p[i]; }
static __device__ __forceinline__ float ldv(const bf16* p, size_t i) { return __bfloat162float(p[i]); }
static __device__ __forceinline__ void stv(float* p, size_t i, float v) { p[i] = v; }
static __device__ __forceinline__ void stv(bf16* p, size_t i, float v) { p[i] = __float2bfloat16(v); }

// round-to-nearest-even f32 -> bf16 bits
static __device__ __forceinline__ unsigned int f2bb(float x) {
  union { float f; unsigned int u; } v;
  v.f = x;
  unsigned int r = v.u + 0x7FFFu + ((v.u >> 16) & 1u);
  return r >> 16;
}
static __device__ __forceinline__ unsigned int packxm(float xt, float mt) {
  return f2bb(xt) | (f2bb(mt) << 16);
}

// ---------------- detect + zero-init (fused) ----------------

__global__ void k_detect_init(const unsigned int* __restrict__ trip_w,
                              const unsigned short* __restrict__ emb_w, int* __restrict__ flag,
                              int* __restrict__ counts, int* __restrict__ stb,
                              int* __restrict__ partial) {
  int tid = threadIdx.x;
  if (blockIdx.x == 0) {
    if (tid < 64) {
      int lane = tid;
      unsigned int acc = 0;
      for (int i = lane; i < 1024; i += 64) acc |= trip_w[2 * i + 1];
      int votes = 0;
      for (int i = lane; i < 2048; i += 64) {
        unsigned short u = emb_w[2 * i];
        int ex = (u >> 7) & 0xFF;
        if (ex >= 90 && ex <= 130) votes++;
      }
      for (int off = 1; off < 64; off <<= 1) {
        acc |= __shfl_xor(acc, off);
        votes += __shfl_xor(votes, off);
      }
      if (lane == 0) {
        flag[0] = (acc == 0) ? 1 : 0;
        flag[1] = (votes < 1024) ? 1 : 0;
      }
    }
    return;
  }
  int g = (blockIdx.x - 1) * 256 + tid;
  for (int i = g; i < R_NUM; i += 159 * 256) counts[i] = 0;
  if (blockIdx.x == 1 && tid < 64) {
    stb[E_NUM + tid] = 0;   // window over-read pad
    partial[tid] = -1;      // lookback-scan sentinel
  }
}

// ---------------- hist + wconv (fused) ----------------

static __device__ __forceinline__ void load_edge(const unsigned int* __restrict__ w, int e,
                                                 int i64, int& h, int& t, int& b) {
  if (i64) {
    h = (int)w[6 * e + 0];
    t = (int)w[6 * e + 2];
    b = (int)w[6 * e + 4];
  } else {
    h = (int)w[3 * e + 0];
    t = (int)w[3 * e + 1];
    b = (int)w[3 * e + 2];
  }
}

__global__ void k_hist_wconv(const unsigned int* __restrict__ trip_w, const int* __restrict__ flag,
                             int* __restrict__ counts, const void* p1w, const void* p1b,
                             const void* apw, const void* apb, const void* abin, const void* avec,
                             const void* aw, const void* ab, const void* rw, const void* rb,
                             float* __restrict__ wbuf) {
  if (blockIdx.x < WCONV_BLOCKS) {
    int i = blockIdx.x * 256 + threadIdx.x;
    if (i >= W_END) return;
    const void* src;
    int off;
    if (i < W_P1B) { src = p1w; off = i - W_P1W; }
    else if (i < W_APW) { src = p1b; off = i - W_P1B; }
    else if (i < W_APB) { src = apw; off = i - W_APW; }
    else if (i < W_ABIN) { src = apb; off = i - W_APB; }
    else if (i < W_AVEC) { src = abin; off = i - W_ABIN; }
    else if (i < W_AW) { src = avec; off = i - W_AVEC; }
    else if (i < W_AB) { src = aw; off = i - W_AW; }
    else if (i < W_RW) { src = ab; off = i - W_AB; }
    else if (i < W_RB) { src = rw; off = i - W_RW; }
    else { src = rb; off = i - W_RB; }
    wbuf[i] = flag[1] ? ((const float*)src)[off] : b2f(((const bf16*)src)[off]);
    return;
  }
  int e = (blockIdx.x - WCONV_BLOCKS) * 256 + threadIdx.x;
  if (e >= E_NUM) return;
  int h, t, b;
  load_edge(trip_w, e, flag[0], h, t, b);
  atomicAdd(&counts[h], 1);
}

// ---------------- single-dispatch lookback scan ----------------
// 40 blocks (all co-resident). Publish own total BEFORE spinning -> no deadlock.

__global__ void k_scan1(const int* __restrict__ counts, int* __restrict__ partial,
                        int* __restrict__ row_ptr) {
  __shared__ int sd[1024];
  __shared__ int soff;
  int tid = threadIdx.x;
  int b = blockIdx.x;
  int idx = b * 1024 + tid;
  int v = (idx < R_NUM) ? counts[idx] : 0;
  sd[tid] = v;
  __syncthreads();
  for (int off = 1; off < 1024; off <<= 1) {
    int t = (tid >= off) ? sd[tid - off] : 0;
    __syncthreads();
    sd[tid] += t;
    __syncthreads();
  }
  if (tid == 0) {
    atomicExch(&partial[b], sd[1023]);  // publish (counts are >= 0)
    int s = 0;
    for (int i = 0; i < b; i++) {
      int p;
      do { p = atomicAdd(&partial[i], 0); } while (p == -1);
      s += p;
    }
    soff = s;
  }
  __syncthreads();
  if (idx < R_NUM) row_ptr[idx] = soff + sd[tid] - v;  // exclusive
}

// scatter bumps row_ptr: afterwards row_ptr[r] == end(r); beg(r) = r ? row_ptr[r-1] : 0
__global__ void k_scatter(const unsigned int* __restrict__ trip_w, const int* __restrict__ flag,
                          int* __restrict__ row_ptr, int* __restrict__ stb) {
  int e = blockIdx.x * 256 + threadIdx.x;
  if (e >= E_NUM) return;
  int h, t, b;
  load_edge(trip_w, e, flag[0], h, t, b);
  int pos = atomicAdd(&row_ptr[h], 1);
  stb[pos] = (t & 0xFFFF) | (b << 16);
}

// ---------------- fused emb0 + packed XM(l0) + HR(l0); 8 rows/thread ----------------
// float4 LDS reads + fused weight streams (DS-instruction diet).

__global__ void __launch_bounds__(256, 4) k_emb0xm_p(const void* __restrict__ A,
                                                     const int* __restrict__ flag,
                                                     const float* __restrict__ wbuf,
                                                     float* __restrict__ emb,
                                                     unsigned int* __restrict__ XMp,
                                                     float2* __restrict__ HR) {
  int j = threadIdx.x & 63;
  int g = threadIdx.x >> 6;
  int r0 = blockIdx.x * 32 + g * 8;
  int f32 = flag[1];
  __shared__ float sA[32][64];
  for (int k = threadIdx.x; k < 2048; k += 256) {
    int rr = k >> 6, cc = k & 63;
    size_t idx = (size_t)(blockIdx.x * 32 + rr) * 64 + cc;
    sA[rr][cc] = f32 ? ((const float*)A)[idx] : b2f(((const bf16*)A)[idx]);
  }
  __syncthreads();
  int base = g * 8;
  float a[8] = {0.f, 0.f, 0.f, 0.f, 0.f, 0.f, 0.f, 0.f};
  {
    const float* W = wbuf + W_P1W;
    for (int i4 = 0; i4 < 64; i4 += 4) {
      float4 ev[8];
#pragma unroll
      for (int n = 0; n < 8; n++) ev[n] = *(const float4*)&sA[base + n][i4];
#pragma unroll
      for (int di = 0; di < 4; di++) {
        float w = W[(i4 + di) * 64 + j];
#pragma unroll
        for (int n = 0; n < 8; n++)
          a[n] = fmaf(((const float*)&ev[n])[di], w, a[n]);
      }
    }
    float bj = wbuf[W_P1B + j];
#pragma unroll
    for (int n = 0; n < 8; n++) {
      a[n] = fmaxf(a[n] + bj, 0.f);
      emb[(size_t)(r0 + n) * 64 + j] = a[n];
    }
  }
  __syncthreads();
#pragma unroll
  for (int n = 0; n < 8; n++) sA[base + n][j] = a[n];
  __syncthreads();
  {
    const float* pwb = wbuf + W_APW + 4096;
    const float* aw = wbuf + W_AW;
    const float* pwt = wbuf + W_APW;
    const float* rw = wbuf + W_RW;
    float axt[8] = {0.f, 0.f, 0.f, 0.f, 0.f, 0.f, 0.f, 0.f};
    float amt[8] = {0.f, 0.f, 0.f, 0.f, 0.f, 0.f, 0.f, 0.f};
    float axh[8] = {0.f, 0.f, 0.f, 0.f, 0.f, 0.f, 0.f, 0.f};
    float ars[8] = {0.f, 0.f, 0.f, 0.f, 0.f, 0.f, 0.f, 0.f};
    for (int i4 = 0; i4 < 64; i4 += 4) {
      float4 ev[8];
#pragma unroll
      for (int n = 0; n < 8; n++) ev[n] = *(const float4*)&sA[base + n][i4];
#pragma unroll
      for (int di = 0; di < 4; di++) {
        int i = i4 + di;
        float wt = pwb[i * 64 + j];
        float wm = aw[i * 64 + j];
        float wh = pwt[i * 64 + j];
        float wr = rw[i * 64 + j];
#pragma unroll
        for (int n = 0; n < 8; n++) {
          float e = ((const float*)&ev[n])[di];
          axt[n] = fmaf(e, wt, axt[n]);
          amt[n] = fmaf(e, wm, amt[n]);
          axh[n] = fmaf(e, wh, axh[n]);
          ars[n] = fmaf(e, wr, ars[n]);
        }
      }
    }
    float abj = wbuf[W_AB + j];
    float pbj = wbuf[W_APB + j];
    float rbj = wbuf[W_RB + j];
#pragma unroll
    for (int n = 0; n < 8; n++) {
      XMp[(size_t)(r0 + n) * 64 + j] = packxm(axt[n], amt[n] + abj);
      HR[(size_t)(r0 + n) * 64 + j] = make_float2(axh[n] + pbj, fmaxf(ars[n] + rbj, 0.f));
    }
  }
}

// ---------------- node-parallel packed XM+HR, layer l; 4 fused streams ----------------

__global__ void __launch_bounds__(256, 4) k_xmhr_p(const float* __restrict__ emb,
                                                   const float* __restrict__ wbuf, int l,
                                                   unsigned int* __restrict__ XMp,
                                                   float2* __restrict__ HR) {
  int j = threadIdx.x & 63;
  int g = threadIdx.x >> 6;
  int r0 = blockIdx.x * 32 + g * 8;
  __shared__ float sE[32][64];
  for (int k = threadIdx.x; k < 2048; k += 256) {
    int rr = k >> 6, cc = k & 63;
    sE[rr][cc] = emb[(size_t)(blockIdx.x * 32 + rr) * 64 + cc];
  }
  __syncthreads();
  int base = g * 8;
  const float* pwb = wbuf + W_APW + l * 8192 + 4096;
  const float* aw = wbuf + W_AW + l * 4096;
  const float* pwt = wbuf + W_APW + l * 8192;
  const float* rw = wbuf + W_RW + l * 4096;
  float axt[8] = {0.f, 0.f, 0.f, 0.f, 0.f, 0.f, 0.f, 0.f};
  float amt[8] = {0.f, 0.f, 0.f, 0.f, 0.f, 0.f, 0.f, 0.f};
  float axh[8] = {0.f, 0.f, 0.f, 0.f, 0.f, 0.f, 0.f, 0.f};
  float ars[8] = {0.f, 0.f, 0.f, 0.f, 0.f, 0.f, 0.f, 0.f};
  for (int i4 = 0; i4 < 64; i4 += 4) {
    float4 ev[8];
#pragma unroll
    for (int n = 0; n < 8; n++) ev[n] = *(const float4*)&sE[base + n][i4];
#pragma unroll
    for (int di = 0; di < 4; di++) {
      int i = i4 + di;
      float wt = pwb[i * 64 + j];
      float wm = aw[i * 64 + j];
      float wh = pwt[i * 64 + j];
      float wr = rw[i * 64 + j];
#pragma unroll
      for (int n = 0; n < 8; n++) {
        float e = ((const float*)&ev[n])[di];
        axt[n] = fmaf(e, wt, axt[n]);
        amt[n] = fmaf(e, wm, amt[n]);
        axh[n] = fmaf(e, wh, axh[n]);
        ars[n] = fmaf(e, wr, ars[n]);
      }
    }
  }
  float abj = wbuf[W_AB + l * 64 + j];
  float pbj = wbuf[W_APB + l * 64 + j];
  float rbj = wbuf[W_RB + l * 64 + j];
#pragma unroll
  for (int n = 0; n < 8; n++) {
    XMp[(size_t)(r0 + n) * 64 + j] = packxm(axt[n], amt[n] + abj);
    HR[(size_t)(r0 + n) * 64 + j] = make_float2(axh[n] + pbj, fmaxf(ars[n] + rbj, 0.f));
  }
}

// ---------------- 2-row edge kernel: 32 gathers in flight ----------------

static __device__ __forceinline__ void consume16(const int* pk, const unsigned int* xp, float xh,
                                                 float av, const float* sab, int hh, int j0,
                                                 int end, float& num, float& den) {
#pragma unroll
  for (int k = 0; k < 16; k++) {
    float xt = __uint_as_float(xp[k] << 16);
    float mt = __uint_as_float(xp[k] & 0xFFFF0000u);
    float z = xh + xt;
    z = (z > 0.f) ? z : 0.2f * z;
    float v = z * av;
    v += __shfl_xor(v, 1);
    v += __shfl_xor(v, 2);
    v += __shfl_xor(v, 4);
    float e = __expf(v + sab[(pk[k] >> 16) * 8 + hh]);
    e = (j0 + k < end) ? e : 0.f;
    den += e;
    num = fmaf(mt, e, num);
  }
}

static __device__ __forceinline__ void edge_window(const int* __restrict__ stb,
                                                   const unsigned int* __restrict__ XMp, int j,
                                                   int end, int lane, int hh, float xh, float av,
                                                   const float* sab, float& num, float& den) {
  int pk[16];
  unsigned int xp[16];
#pragma unroll
  for (int k = 0; k < 16; k++) pk[k] = stb[j + k];
#pragma unroll
  for (int k = 0; k < 16; k++) xp[k] = XMp[(size_t)(pk[k] & 0xFFFF) * 64 + lane];
  consume16(pk, xp, xh, av, sab, hh, j, end, num, den);
}

__global__ void __launch_bounds__(256, 4) k_edge_lean(
    const int* __restrict__ row_ptr, const int* __restrict__ stb,
    const unsigned int* __restrict__ XMp, const float2* __restrict__ HR,
    const float* __restrict__ wbuf, int l, float* __restrict__ emb) {
  __shared__ float sab[80];
  int tid = threadIdx.x;
  int lane = tid & 63;
  int w = tid >> 6;
  int hh = lane >> 3;
  if (tid < 80) {
    float a = wbuf[W_ABIN + l * 80 + tid];
    sab[tid] = (a > 0.f) ? a : 0.2f * a;
  }
  __syncthreads();
  float av = wbuf[W_AVEC + l * 64 + lane];

  int r = blockIdx.x * 8 + w * 2;  // rows r, r+1 (contiguous in stb)
  float2 hrA = HR[(size_t)r * 64 + lane];
  float2 hrB = HR[(size_t)(r + 1) * 64 + lane];
  int begA = (r == 0) ? 0 : row_ptr[r - 1];
  int endA = row_ptr[r];
  int endB = row_ptr[r + 1];
  begA = __builtin_amdgcn_readfirstlane(begA);
  endA = __builtin_amdgcn_readfirstlane(endA);
  endB = __builtin_amdgcn_readfirstlane(endB);
  int begB = endA;

  float numA = 0.f, denA = 0.f, numB = 0.f, denB = 0.f;
  {  // combined first super-window: 32 gathers issued before any consume
    int pkA[16], pkB[16];
    unsigned int xpA[16], xpB[16];
#pragma unroll
    for (int k = 0; k < 16; k++) pkA[k] = stb[begA + k];
#pragma unroll
    for (int k = 0; k < 16; k++) pkB[k] = stb[begB + k];
#pragma unroll
    for (int k = 0; k < 16; k++) xpA[k] = XMp[(size_t)(pkA[k] & 0xFFFF) * 64 + lane];
#pragma unroll
    for (int k = 0; k < 16; k++) xpB[k] = XMp[(size_t)(pkB[k] & 0xFFFF) * 64 + lane];
    consume16(pkA, xpA, hrA.x, av, sab, hh, begA, endA, numA, denA);
    consume16(pkB, xpB, hrB.x, av, sab, hh, begB, endB, numB, denB);
  }
  for (int j = begA + 16; j < endA; j += 16)
    edge_window(stb, XMp, j, endA, lane, hh, hrA.x, av, sab, numA, denA);
  for (int j = begB + 16; j < endB; j += 16)
    edge_window(stb, XMp, j, endB, lane, hh, hrB.x, av, sab, numB, denB);

  emb[(size_t)r * 64 + lane] = fmaxf(numA / (denA + 1e-16f), 0.f) + hrA.y;
  emb[(size_t)(r + 1) * 64 + lane] = fmaxf(numB / (denB + 1e-16f), 0.f) + hrB.y;
}

// ---------------- fallback kernels (XM1 / Plan D paths) ----------------

__global__ void k_emb0(const void* __restrict__ A, const int* __restrict__ flag,
                       const float* __restrict__ wbuf, float* __restrict__ emb) {
  int j = threadIdx.x & 63;
  int g = threadIdx.x >> 6;
  int r0 = blockIdx.x * 16 + g * 4;
  int f32 = flag[1];
  __shared__ float sA[16][64];
  for (int k = threadIdx.x; k < 1024; k += 256) {
    int rr = k >> 6, cc = k & 63;
    size_t idx = (size_t)(blockIdx.x * 16 + rr) * 64 + cc;
    sA[rr][cc] = f32 ? ((const float*)A)[idx] : b2f(((const bf16*)A)[idx]);
  }
  __syncthreads();
  const float* W = wbuf + W_P1W;
  float a[4] = {0.f, 0.f, 0.f, 0.f};
  int base = g * 4;
  for (int i = 0; i < 64; i++) {
    float w = W[i * 64 + j];
#pragma unroll
    for (int n = 0; n < 4; n++) a[n] = fmaf(sA[base + n][i], w, a[n]);
  }
  float bj = wbuf[W_P1B + j];
#pragma unroll
  for (int n = 0; n < 4; n++)
    emb[(size_t)(r0 + n) * 64 + j] = fmaxf(a[n] + bj, 0.f);
}

__global__ void k_xm(const float* __restrict__ emb, const float* __restrict__ wbuf, int l,
                     float2* __restrict__ XM) {
  int j = threadIdx.x & 63;
  int g = threadIdx.x >> 6;
  int r0 = blockIdx.x * 16 + g * 4;
  __shared__ float sE[16][64];
  for (int k = threadIdx.x; k < 1024; k += 256) {
    int rr = k >> 6, cc = k & 63;
    sE[rr][cc] = emb[(size_t)(blockIdx.x * 16 + rr) * 64 + cc];
  }
  __syncthreads();
  const float* pwb = wbuf + W_APW + l * 8192 + 4096;
  const float* aw = wbuf + W_AW + l * 4096;
  float axt[4] = {0.f, 0.f, 0.f, 0.f};
  float amt[4] = {0.f, 0.f, 0.f, 0.f};
  int base = g * 4;
  for (int i = 0; i < 64; i++) {
    float wt = pwb[i * 64 + j];
    float wm = aw[i * 64 + j];
#pragma unroll
    for (int n = 0; n < 4; n++) {
      float e = sE[base + n][i];
      axt[n] = fmaf(e, wt, axt[n]);
      amt[n] = fmaf(e, wm, amt[n]);
    }
  }
  float abj = wbuf[W_AB + l * 64 + j];
#pragma unroll
  for (int n = 0; n < 4; n++)
    XM[(size_t)(r0 + n) * 64 + j] = make_float2(axt[n], amt[n] + abj);
}

__global__ void __launch_bounds__(256, 4) k_edge_f(
    const int* __restrict__ row_ptr, const int* __restrict__ stb, const float2* __restrict__ XM,
    const float* __restrict__ wbuf, int l, float* __restrict__ emb) {
  __shared__ float sab[80];
  int tid = threadIdx.x;
  int lane = tid & 63;
  int w = tid >> 6;
  int hh = lane >> 3;
  if (tid < 80) {
    float a = wbuf[W_ABIN + l * 80 + tid];
    sab[tid] = (a > 0.f) ? a : 0.2f * a;
  }
  __syncthreads();

  const float* pwt = wbuf + W_APW + l * 8192;
  const float* rwp = wbuf + W_RW + l * 4096;
  float av = wbuf[W_AVEC + l * 64 + lane];
  float xh0 = wbuf[W_APB + l * 64 + lane];
  float res0 = wbuf[W_RB + l * 64 + lane];

  int r0 = blockIdx.x * 16 + w * 4;
  for (int rr = 0; rr < 4; rr++) {
    int r = r0 + rr;
    float ev = emb[(size_t)r * 64 + lane];
    float xh = xh0, res = res0;
#pragma unroll 16
    for (int i = 0; i < 64; i++) {
      float e = __shfl(ev, i);
      xh = fmaf(e, pwt[i * 64 + lane], xh);
      res = fmaf(e, rwp[i * 64 + lane], res);
    }
    res = fmaxf(res, 0.f);

    int beg = (r == 0) ? 0 : row_ptr[r - 1];
    int end = row_ptr[r];
    beg = __builtin_amdgcn_readfirstlane(beg);
    end = __builtin_amdgcn_readfirstlane(end);

    float num = 0.f, den = 0.f;
    for (int j = beg; j < end; j += 16) {
      int pk[16];
      float2 xmv[16];
#pragma unroll
      for (int k = 0; k < 16; k++) pk[k] = stb[j + k];
#pragma unroll
      for (int k = 0; k < 16; k++) xmv[k] = XM[(size_t)(pk[k] & 0xFFFF) * 64 + lane];
#pragma unroll
      for (int k = 0; k < 16; k++) {
        float z = xh + xmv[k].x;
        z = (z > 0.f) ? z : 0.2f * z;
        float v = z * av;
        v += __shfl_xor(v, 1);
        v += __shfl_xor(v, 2);
        v += __shfl_xor(v, 4);
        float e = __expf(v + sab[(pk[k] >> 16) * 8 + hh]);
        e = (j + k < end) ? e : 0.f;
        den += e;
        num = fmaf(xmv[k].y, e, num);
      }
    }
    emb[(size_t)r * 64 + lane] = fmaxf(num / (den + 1e-16f), 0.f) + res;
  }
}

static __device__ __forceinline__ float dotcol(const float* __restrict__ Wm, float val, int lane) {
  float acc = 0.f;
  for (int i = 0; i < 64; i++) acc = fmaf(__shfl(val, i), Wm[i * 64 + lane], acc);
  return acc;
}

template <typename TIN, typename TOUT>
__global__ void k_edge_d(const int* __restrict__ row_ptr, const int* __restrict__ stb,
                         const float* __restrict__ wbuf, int l, const TIN* __restrict__ emb_in,
                         TOUT* __restrict__ emb_out) {
  __shared__ float sab[80];
  int tid = threadIdx.x;
  int lane = tid & 63;
  int w = tid >> 6;
  int r = blockIdx.x * 4 + w;
  int hh = lane >> 3;
  if (tid < 80) {
    float a = wbuf[W_ABIN + l * 80 + tid];
    sab[tid] = (a > 0.f) ? a : 0.2f * a;
  }
  __syncthreads();
  const float* pwt = wbuf + W_APW + l * 8192;
  const float* pwb = pwt + 4096;
  const float* aw = wbuf + W_AW + l * 4096;
  const float* rw = wbuf + W_RW + l * 4096;

  float ev = ldv(emb_in, (size_t)r * 64 + lane);
  float xh = wbuf[W_APB + l * 64 + lane];
  float res = wbuf[W_RB + l * 64 + lane];
  for (int i = 0; i < 64; i++) {
    float e = __shfl(ev, i);
    xh = fmaf(e, pwt[i * 64 + lane], xh);
    res = fmaf(e, rw[i * 64 + lane], res);
  }
  res = fmaxf(res, 0.f);
  float av = wbuf[W_AVEC + l * 64 + lane];
  float abl = wbuf[W_AB + l * 64 + lane];

  int beg = (r == 0) ? 0 : row_ptr[r - 1];
  int end = row_ptr[r];
  float num = 0.f, den = 0.f;
  for (int j = beg; j < end; j++) {
    int p = stb[j];
    int t = p & 0xFFFF;
    float tv = ldv(emb_in, (size_t)t * 64 + lane);
    float z = xh + dotcol(pwb, tv, lane);
    z = (z > 0.f) ? z : 0.2f * z;
    float v = z * av;
    v += __shfl_xor(v, 1);
    v += __shfl_xor(v, 2);
    v += __shfl_xor(v, 4);
    float e = __expf(v + sab[(p >> 16) * 8 + hh]);
    den += e;
    float mt = dotcol(aw, tv, lane) + abl;
    num = fmaf(mt, e, num);
  }
  stv(emb_out, (size_t)r * 64 + lane, fmaxf(num / (den + 1e-16f), 0.f) + res);
}

// ---------------- launch ----------------

extern "C" void kernel_launch(void* const* d_in, const int* in_sizes, int n_in,
                              void* d_out, int out_size, void* d_ws, size_t ws_size,
                              hipStream_t stream) {
  const unsigned int* trip_w = (const unsigned int*)d_in[0];
  const void* rel_emb = d_in[1];
  float* emb = (float*)d_out;

  char* ws = (char*)d_ws;
  int* flag = (int*)(ws + O_FLAG);
  float* wbuf = (float*)(ws + O_WBUF);
  int* row_ptr = (int*)(ws + O_ROWP);
  int* counts = (int*)(ws + O_CNTS);
  int* partial = (int*)(ws + O_PART);
  int* stb = (int*)(ws + O_STB);
  char* big = ws + O_BIG;

  k_detect_init<<<160, 256, 0, stream>>>(trip_w, (const unsigned short*)rel_emb, flag, counts,
                                         stb, partial);
  int eb_blocks = (E_NUM + 255) / 256;
  k_hist_wconv<<<WCONV_BLOCKS + eb_blocks, 256, 0, stream>>>(
      trip_w, flag, counts, d_in[2], d_in[3], d_in[4], d_in[5], d_in[6], d_in[7], d_in[8],
      d_in[9], d_in[10], d_in[11], wbuf);
  k_scan1<<<40, 1024, 0, stream>>>(counts, partial, row_ptr);
  k_scatter<<<eb_blocks, 256, 0, stream>>>(trip_w, flag, row_ptr, stb);

  if (ws_size >= NEED_LEAN) {
    unsigned int* XMp = (unsigned int*)big;
    float2* HR = (float2*)(big + XMP_BYTES);
    k_emb0xm_p<<<R_NUM / 32, 256, 0, stream>>>(rel_emb, flag, wbuf, emb, XMp, HR);
    k_edge_lean<<<R_NUM / 8, 256, 0, stream>>>(row_ptr, stb, XMp, HR, wbuf, 0, emb);
    k_xmhr_p<<<R_NUM / 32, 256, 0, stream>>>(emb, wbuf, 1, XMp, HR);
    k_edge_lean<<<R_NUM / 8, 256, 0, stream>>>(row_ptr, stb, XMp, HR, wbuf, 1, emb);
  } else if (ws_size >= NEED_XM1) {
    float2* XM = (float2*)big;
    k_emb0<<<R_NUM / 16, 256, 0, stream>>>(rel_emb, flag, wbuf, emb);
    k_xm<<<R_NUM / 16, 256, 0, stream>>>(emb, wbuf, 0, XM);
    k_edge_f<<<R_NUM / 16, 256, 0, stream>>>(row_ptr, stb, XM, wbuf, 0, emb);
    k_xm<<<R_NUM / 16, 256, 0, stream>>>(emb, wbuf, 1, XM);
    k_edge_f<<<R_NUM / 16, 256, 0, stream>>>(row_ptr, stb, XM, wbuf, 1, emb);
  } else {
    k_emb0<<<R_NUM / 16, 256, 0, stream>>>(rel_emb, flag, wbuf, emb);
    bf16* embB = (bf16*)big;
    k_edge_d<float, bf16><<<R_NUM / 4, 256, 0, stream>>>(row_ptr, stb, wbuf, 0, emb, embB);
    k_edge_d<bf16, float><<<R_NUM / 4, 256, 0, stream>>>(row_ptr, stb, wbuf, 1, embB, emb);
  }
}

// Round 15
// 261.772 us; speedup vs baseline: 1.0797x; 1.0718x over previous
//
#include <hip/hip_runtime.h>
#include <hip/hip_bf16.h>

typedef __hip_bfloat16 bf16;

#define R_NUM 40000
#define E_NUM 500000

// wbuf layout (f32 element offsets)
#define W_P1W 0
#define W_P1B 4096
#define W_APW 4160    // 2*128*64
#define W_APB 20544   // 2*64
#define W_ABIN 20672  // 2*10*8
#define W_AVEC 20832  // 2*8*8
#define W_AW 20960    // 2*64*64
#define W_AB 29152
#define W_RW 29280
#define W_RB 37472
#define W_END 37600
#define WCONV_BLOCKS 147  // ceil(W_END/256)

// ws byte offsets
#define O_FLAG 0
#define O_WBUF 256
#define O_ROWP 150784
#define O_CNTS 310784
#define O_PART 470784
#define O_STB 471040
#define O_BIG 2471296  // stb + 64-int zero pad
#define XMP_BYTES 10240000ull   // R*64 u32
#define HR_BYTES 20480000ull    // R*64 float2
#define XM32_BYTES 20480000ull  // R*64 float2 (fallback)
#define NEED_LEAN (O_BIG + XMP_BYTES + HR_BYTES)
#define NEED_XM1 (O_BIG + XM32_BYTES)

static __device__ __forceinline__ float b2f(bf16 x) { return __bfloat162float(x); }
static __device__ __forceinline__ float ldv(const float* p, size_t i) { return p[i]; }
static __device__ __forceinline__ float ldv(const bf16* p, size_t i) { return __bfloat162float(p[i]); }
static __device__ __forceinline__ void stv(float* p, size_t i, float v) { p[i] = v; }
static __device__ __forceinline__ void stv(bf16* p, size_t i, float v) { p[i] = __float2bfloat16(v); }

// round-to-nearest-even f32 -> bf16 bits
static __device__ __forceinline__ unsigned int f2bb(float x) {
  union { float f; unsigned int u; } v;
  v.f = x;
  unsigned int r = v.u + 0x7FFFu + ((v.u >> 16) & 1u);
  return r >> 16;
}
static __device__ __forceinline__ unsigned int packxm(float xt, float mt) {
  return f2bb(xt) | (f2bb(mt) << 16);
}

// ---------------- detect + zero-init (fused) ----------------

__global__ void k_detect_init(const unsigned int* __restrict__ trip_w,
                              const unsigned short* __restrict__ emb_w, int* __restrict__ flag,
                              int* __restrict__ counts, int* __restrict__ stb,
                              int* __restrict__ partial) {
  int tid = threadIdx.x;
  if (blockIdx.x == 0) {
    if (tid < 64) {
      int lane = tid;
      unsigned int acc = 0;
      for (int i = lane; i < 1024; i += 64) acc |= trip_w[2 * i + 1];
      int votes = 0;
      for (int i = lane; i < 2048; i += 64) {
        unsigned short u = emb_w[2 * i];
        int ex = (u >> 7) & 0xFF;
        if (ex >= 90 && ex <= 130) votes++;
      }
      for (int off = 1; off < 64; off <<= 1) {
        acc |= __shfl_xor(acc, off);
        votes += __shfl_xor(votes, off);
      }
      if (lane == 0) {
        flag[0] = (acc == 0) ? 1 : 0;
        flag[1] = (votes < 1024) ? 1 : 0;
      }
    }
    return;
  }
  int g = (blockIdx.x - 1) * 256 + tid;
  for (int i = g; i < R_NUM; i += 159 * 256) counts[i] = 0;
  if (blockIdx.x == 1 && tid < 64) {
    stb[E_NUM + tid] = 0;   // window over-read pad
    partial[tid] = -1;      // lookback-scan sentinel
  }
}

// ---------------- hist + wconv (fused) ----------------

static __device__ __forceinline__ void load_edge(const unsigned int* __restrict__ w, int e,
                                                 int i64, int& h, int& t, int& b) {
  if (i64) {
    h = (int)w[6 * e + 0];
    t = (int)w[6 * e + 2];
    b = (int)w[6 * e + 4];
  } else {
    h = (int)w[3 * e + 0];
    t = (int)w[3 * e + 1];
    b = (int)w[3 * e + 2];
  }
}

__global__ void k_hist_wconv(const unsigned int* __restrict__ trip_w, const int* __restrict__ flag,
                             int* __restrict__ counts, const void* p1w, const void* p1b,
                             const void* apw, const void* apb, const void* abin, const void* avec,
                             const void* aw, const void* ab, const void* rw, const void* rb,
                             float* __restrict__ wbuf) {
  if (blockIdx.x < WCONV_BLOCKS) {
    int i = blockIdx.x * 256 + threadIdx.x;
    if (i >= W_END) return;
    const void* src;
    int off;
    if (i < W_P1B) { src = p1w; off = i - W_P1W; }
    else if (i < W_APW) { src = p1b; off = i - W_P1B; }
    else if (i < W_APB) { src = apw; off = i - W_APW; }
    else if (i < W_ABIN) { src = apb; off = i - W_APB; }
    else if (i < W_AVEC) { src = abin; off = i - W_ABIN; }
    else if (i < W_AW) { src = avec; off = i - W_AVEC; }
    else if (i < W_AB) { src = aw; off = i - W_AW; }
    else if (i < W_RW) { src = ab; off = i - W_AB; }
    else if (i < W_RB) { src = rw; off = i - W_RW; }
    else { src = rb; off = i - W_RB; }
    wbuf[i] = flag[1] ? ((const float*)src)[off] : b2f(((const bf16*)src)[off]);
    return;
  }
  int e = (blockIdx.x - WCONV_BLOCKS) * 256 + threadIdx.x;
  if (e >= E_NUM) return;
  int h, t, b;
  load_edge(trip_w, e, flag[0], h, t, b);
  atomicAdd(&counts[h], 1);
}

// ---------------- single-dispatch lookback scan ----------------
// 40 blocks (all co-resident). Publish own total BEFORE spinning -> no deadlock.

__global__ void k_scan1(const int* __restrict__ counts, int* __restrict__ partial,
                        int* __restrict__ row_ptr) {
  __shared__ int sd[1024];
  __shared__ int soff;
  int tid = threadIdx.x;
  int b = blockIdx.x;
  int idx = b * 1024 + tid;
  int v = (idx < R_NUM) ? counts[idx] : 0;
  sd[tid] = v;
  __syncthreads();
  for (int off = 1; off < 1024; off <<= 1) {
    int t = (tid >= off) ? sd[tid - off] : 0;
    __syncthreads();
    sd[tid] += t;
    __syncthreads();
  }
  if (tid == 0) {
    atomicExch(&partial[b], sd[1023]);  // publish (counts are >= 0)
    int s = 0;
    for (int i = 0; i < b; i++) {
      int p;
      do { p = atomicAdd(&partial[i], 0); } while (p == -1);
      s += p;
    }
    soff = s;
  }
  __syncthreads();
  if (idx < R_NUM) row_ptr[idx] = soff + sd[tid] - v;  // exclusive
}

// scatter bumps row_ptr: afterwards row_ptr[r] == end(r); beg(r) = r ? row_ptr[r-1] : 0
__global__ void k_scatter(const unsigned int* __restrict__ trip_w, const int* __restrict__ flag,
                          int* __restrict__ row_ptr, int* __restrict__ stb) {
  int e = blockIdx.x * 256 + threadIdx.x;
  if (e >= E_NUM) return;
  int h, t, b;
  load_edge(trip_w, e, flag[0], h, t, b);
  int pos = atomicAdd(&row_ptr[h], 1);
  stb[pos] = (t & 0xFFFF) | (b << 16);
}

// ---------------- fused emb0 + packed XM(l0) + HR(l0); 8 rows/thread ----------------
// float4 LDS reads + fused weight streams (DS-instruction diet).

__global__ void __launch_bounds__(256, 4) k_emb0xm_p(const void* __restrict__ A,
                                                     const int* __restrict__ flag,
                                                     const float* __restrict__ wbuf,
                                                     float* __restrict__ emb,
                                                     unsigned int* __restrict__ XMp,
                                                     float2* __restrict__ HR) {
  int j = threadIdx.x & 63;
  int g = threadIdx.x >> 6;
  int r0 = blockIdx.x * 32 + g * 8;
  int f32 = flag[1];
  __shared__ float sA[32][64];
  for (int k = threadIdx.x; k < 2048; k += 256) {
    int rr = k >> 6, cc = k & 63;
    size_t idx = (size_t)(blockIdx.x * 32 + rr) * 64 + cc;
    sA[rr][cc] = f32 ? ((const float*)A)[idx] : b2f(((const bf16*)A)[idx]);
  }
  __syncthreads();
  int base = g * 8;
  float a[8] = {0.f, 0.f, 0.f, 0.f, 0.f, 0.f, 0.f, 0.f};
  {
    const float* W = wbuf + W_P1W;
    for (int i4 = 0; i4 < 64; i4 += 4) {
      float4 ev[8];
#pragma unroll
      for (int n = 0; n < 8; n++) ev[n] = *(const float4*)&sA[base + n][i4];
#pragma unroll
      for (int di = 0; di < 4; di++) {
        float w = W[(i4 + di) * 64 + j];
#pragma unroll
        for (int n = 0; n < 8; n++)
          a[n] = fmaf(((const float*)&ev[n])[di], w, a[n]);
      }
    }
    float bj = wbuf[W_P1B + j];
#pragma unroll
    for (int n = 0; n < 8; n++) {
      a[n] = fmaxf(a[n] + bj, 0.f);
      emb[(size_t)(r0 + n) * 64 + j] = a[n];
    }
  }
  __syncthreads();
#pragma unroll
  for (int n = 0; n < 8; n++) sA[base + n][j] = a[n];
  __syncthreads();
  {
    const float* pwb = wbuf + W_APW + 4096;
    const float* aw = wbuf + W_AW;
    const float* pwt = wbuf + W_APW;
    const float* rw = wbuf + W_RW;
    float axt[8] = {0.f, 0.f, 0.f, 0.f, 0.f, 0.f, 0.f, 0.f};
    float amt[8] = {0.f, 0.f, 0.f, 0.f, 0.f, 0.f, 0.f, 0.f};
    float axh[8] = {0.f, 0.f, 0.f, 0.f, 0.f, 0.f, 0.f, 0.f};
    float ars[8] = {0.f, 0.f, 0.f, 0.f, 0.f, 0.f, 0.f, 0.f};
    for (int i4 = 0; i4 < 64; i4 += 4) {
      float4 ev[8];
#pragma unroll
      for (int n = 0; n < 8; n++) ev[n] = *(const float4*)&sA[base + n][i4];
#pragma unroll
      for (int di = 0; di < 4; di++) {
        int i = i4 + di;
        float wt = pwb[i * 64 + j];
        float wm = aw[i * 64 + j];
        float wh = pwt[i * 64 + j];
        float wr = rw[i * 64 + j];
#pragma unroll
        for (int n = 0; n < 8; n++) {
          float e = ((const float*)&ev[n])[di];
          axt[n] = fmaf(e, wt, axt[n]);
          amt[n] = fmaf(e, wm, amt[n]);
          axh[n] = fmaf(e, wh, axh[n]);
          ars[n] = fmaf(e, wr, ars[n]);
        }
      }
    }
    float abj = wbuf[W_AB + j];
    float pbj = wbuf[W_APB + j];
    float rbj = wbuf[W_RB + j];
#pragma unroll
    for (int n = 0; n < 8; n++) {
      XMp[(size_t)(r0 + n) * 64 + j] = packxm(axt[n], amt[n] + abj);
      HR[(size_t)(r0 + n) * 64 + j] = make_float2(axh[n] + pbj, fmaxf(ars[n] + rbj, 0.f));
    }
  }
}

// ---------------- node-parallel packed XM+HR, layer l; 4 fused streams ----------------

__global__ void __launch_bounds__(256, 4) k_xmhr_p(const float* __restrict__ emb,
                                                   const float* __restrict__ wbuf, int l,
                                                   unsigned int* __restrict__ XMp,
                                                   float2* __restrict__ HR) {
  int j = threadIdx.x & 63;
  int g = threadIdx.x >> 6;
  int r0 = blockIdx.x * 32 + g * 8;
  __shared__ float sE[32][64];
  for (int k = threadIdx.x; k < 2048; k += 256) {
    int rr = k >> 6, cc = k & 63;
    sE[rr][cc] = emb[(size_t)(blockIdx.x * 32 + rr) * 64 + cc];
  }
  __syncthreads();
  int base = g * 8;
  const float* pwb = wbuf + W_APW + l * 8192 + 4096;
  const float* aw = wbuf + W_AW + l * 4096;
  const float* pwt = wbuf + W_APW + l * 8192;
  const float* rw = wbuf + W_RW + l * 4096;
  float axt[8] = {0.f, 0.f, 0.f, 0.f, 0.f, 0.f, 0.f, 0.f};
  float amt[8] = {0.f, 0.f, 0.f, 0.f, 0.f, 0.f, 0.f, 0.f};
  float axh[8] = {0.f, 0.f, 0.f, 0.f, 0.f, 0.f, 0.f, 0.f};
  float ars[8] = {0.f, 0.f, 0.f, 0.f, 0.f, 0.f, 0.f, 0.f};
  for (int i4 = 0; i4 < 64; i4 += 4) {
    float4 ev[8];
#pragma unroll
    for (int n = 0; n < 8; n++) ev[n] = *(const float4*)&sE[base + n][i4];
#pragma unroll
    for (int di = 0; di < 4; di++) {
      int i = i4 + di;
      float wt = pwb[i * 64 + j];
      float wm = aw[i * 64 + j];
      float wh = pwt[i * 64 + j];
      float wr = rw[i * 64 + j];
#pragma unroll
      for (int n = 0; n < 8; n++) {
        float e = ((const float*)&ev[n])[di];
        axt[n] = fmaf(e, wt, axt[n]);
        amt[n] = fmaf(e, wm, amt[n]);
        axh[n] = fmaf(e, wh, axh[n]);
        ars[n] = fmaf(e, wr, ars[n]);
      }
    }
  }
  float abj = wbuf[W_AB + l * 64 + j];
  float pbj = wbuf[W_APB + l * 64 + j];
  float rbj = wbuf[W_RB + l * 64 + j];
#pragma unroll
  for (int n = 0; n < 8; n++) {
    XMp[(size_t)(r0 + n) * 64 + j] = packxm(axt[n], amt[n] + abj);
    HR[(size_t)(r0 + n) * 64 + j] = make_float2(axh[n] + pbj, fmaxf(ars[n] + rbj, 0.f));
  }
}

// ---------------- 1-row lean edge kernel (R12-proven): window-16 packed gathers ----------------

__global__ void __launch_bounds__(256, 4) k_edge_lean(
    const int* __restrict__ row_ptr, const int* __restrict__ stb,
    const unsigned int* __restrict__ XMp, const float2* __restrict__ HR,
    const float* __restrict__ wbuf, int l, float* __restrict__ emb) {
  __shared__ float sab[80];
  int tid = threadIdx.x;
  int lane = tid & 63;
  int w = tid >> 6;
  int hh = lane >> 3;
  if (tid < 80) {
    float a = wbuf[W_ABIN + l * 80 + tid];
    sab[tid] = (a > 0.f) ? a : 0.2f * a;
  }
  __syncthreads();
  float av = wbuf[W_AVEC + l * 64 + lane];

  int r = blockIdx.x * 4 + w;
  float2 hr = HR[(size_t)r * 64 + lane];
  int beg = (r == 0) ? 0 : row_ptr[r - 1];
  int end = row_ptr[r];
  beg = __builtin_amdgcn_readfirstlane(beg);
  end = __builtin_amdgcn_readfirstlane(end);

  float xh = hr.x;
  float num = 0.f, den = 0.f;
  for (int j = beg; j < end; j += 16) {
    int pk[16];
    unsigned int xp[16];
#pragma unroll
    for (int k = 0; k < 16; k++) pk[k] = stb[j + k];  // scalar loads
#pragma unroll
    for (int k = 0; k < 16; k++)
      xp[k] = XMp[(size_t)(pk[k] & 0xFFFF) * 64 + lane];  // 16 gathers in flight
#pragma unroll
    for (int k = 0; k < 16; k++) {
      float xt = __uint_as_float(xp[k] << 16);
      float mt = __uint_as_float(xp[k] & 0xFFFF0000u);
      float z = xh + xt;
      z = (z > 0.f) ? z : 0.2f * z;
      float v = z * av;
      v += __shfl_xor(v, 1);
      v += __shfl_xor(v, 2);
      v += __shfl_xor(v, 4);
      float e = __expf(v + sab[(pk[k] >> 16) * 8 + hh]);
      e = (j + k < end) ? e : 0.f;
      den += e;
      num = fmaf(mt, e, num);
    }
  }
  emb[(size_t)r * 64 + lane] = fmaxf(num / (den + 1e-16f), 0.f) + hr.y;
}

// ---------------- fallback kernels (XM1 / Plan D paths) ----------------

__global__ void k_emb0(const void* __restrict__ A, const int* __restrict__ flag,
                       const float* __restrict__ wbuf, float* __restrict__ emb) {
  int j = threadIdx.x & 63;
  int g = threadIdx.x >> 6;
  int r0 = blockIdx.x * 16 + g * 4;
  int f32 = flag[1];
  __shared__ float sA[16][64];
  for (int k = threadIdx.x; k < 1024; k += 256) {
    int rr = k >> 6, cc = k & 63;
    size_t idx = (size_t)(blockIdx.x * 16 + rr) * 64 + cc;
    sA[rr][cc] = f32 ? ((const float*)A)[idx] : b2f(((const bf16*)A)[idx]);
  }
  __syncthreads();
  const float* W = wbuf + W_P1W;
  float a[4] = {0.f, 0.f, 0.f, 0.f};
  int base = g * 4;
  for (int i = 0; i < 64; i++) {
    float w = W[i * 64 + j];
#pragma unroll
    for (int n = 0; n < 4; n++) a[n] = fmaf(sA[base + n][i], w, a[n]);
  }
  float bj = wbuf[W_P1B + j];
#pragma unroll
  for (int n = 0; n < 4; n++)
    emb[(size_t)(r0 + n) * 64 + j] = fmaxf(a[n] + bj, 0.f);
}

__global__ void k_xm(const float* __restrict__ emb, const float* __restrict__ wbuf, int l,
                     float2* __restrict__ XM) {
  int j = threadIdx.x & 63;
  int g = threadIdx.x >> 6;
  int r0 = blockIdx.x * 16 + g * 4;
  __shared__ float sE[16][64];
  for (int k = threadIdx.x; k < 1024; k += 256) {
    int rr = k >> 6, cc = k & 63;
    sE[rr][cc] = emb[(size_t)(blockIdx.x * 16 + rr) * 64 + cc];
  }
  __syncthreads();
  const float* pwb = wbuf + W_APW + l * 8192 + 4096;
  const float* aw = wbuf + W_AW + l * 4096;
  float axt[4] = {0.f, 0.f, 0.f, 0.f};
  float amt[4] = {0.f, 0.f, 0.f, 0.f};
  int base = g * 4;
  for (int i = 0; i < 64; i++) {
    float wt = pwb[i * 64 + j];
    float wm = aw[i * 64 + j];
#pragma unroll
    for (int n = 0; n < 4; n++) {
      float e = sE[base + n][i];
      axt[n] = fmaf(e, wt, axt[n]);
      amt[n] = fmaf(e, wm, amt[n]);
    }
  }
  float abj = wbuf[W_AB + l * 64 + j];
#pragma unroll
  for (int n = 0; n < 4; n++)
    XM[(size_t)(r0 + n) * 64 + j] = make_float2(axt[n], amt[n] + abj);
}

__global__ void __launch_bounds__(256, 4) k_edge_f(
    const int* __restrict__ row_ptr, const int* __restrict__ stb, const float2* __restrict__ XM,
    const float* __restrict__ wbuf, int l, float* __restrict__ emb) {
  __shared__ float sab[80];
  int tid = threadIdx.x;
  int lane = tid & 63;
  int w = tid >> 6;
  int hh = lane >> 3;
  if (tid < 80) {
    float a = wbuf[W_ABIN + l * 80 + tid];
    sab[tid] = (a > 0.f) ? a : 0.2f * a;
  }
  __syncthreads();

  const float* pwt = wbuf + W_APW + l * 8192;
  const float* rwp = wbuf + W_RW + l * 4096;
  float av = wbuf[W_AVEC + l * 64 + lane];
  float xh0 = wbuf[W_APB + l * 64 + lane];
  float res0 = wbuf[W_RB + l * 64 + lane];

  int r0 = blockIdx.x * 16 + w * 4;
  for (int rr = 0; rr < 4; rr++) {
    int r = r0 + rr;
    float ev = emb[(size_t)r * 64 + lane];
    float xh = xh0, res = res0;
#pragma unroll 16
    for (int i = 0; i < 64; i++) {
      float e = __shfl(ev, i);
      xh = fmaf(e, pwt[i * 64 + lane], xh);
      res = fmaf(e, rwp[i * 64 + lane], res);
    }
    res = fmaxf(res, 0.f);

    int beg = (r == 0) ? 0 : row_ptr[r - 1];
    int end = row_ptr[r];
    beg = __builtin_amdgcn_readfirstlane(beg);
    end = __builtin_amdgcn_readfirstlane(end);

    float num = 0.f, den = 0.f;
    for (int j = beg; j < end; j += 16) {
      int pk[16];
      float2 xmv[16];
#pragma unroll
      for (int k = 0; k < 16; k++) pk[k] = stb[j + k];
#pragma unroll
      for (int k = 0; k < 16; k++) xmv[k] = XM[(size_t)(pk[k] & 0xFFFF) * 64 + lane];
#pragma unroll
      for (int k = 0; k < 16; k++) {
        float z = xh + xmv[k].x;
        z = (z > 0.f) ? z : 0.2f * z;
        float v = z * av;
        v += __shfl_xor(v, 1);
        v += __shfl_xor(v, 2);
        v += __shfl_xor(v, 4);
        float e = __expf(v + sab[(pk[k] >> 16) * 8 + hh]);
        e = (j + k < end) ? e : 0.f;
        den += e;
        num = fmaf(xmv[k].y, e, num);
      }
    }
    emb[(size_t)r * 64 + lane] = fmaxf(num / (den + 1e-16f), 0.f) + res;
  }
}

static __device__ __forceinline__ float dotcol(const float* __restrict__ Wm, float val, int lane) {
  float acc = 0.f;
  for (int i = 0; i < 64; i++) acc = fmaf(__shfl(val, i), Wm[i * 64 + lane], acc);
  return acc;
}

template <typename TIN, typename TOUT>
__global__ void k_edge_d(const int* __restrict__ row_ptr, const int* __restrict__ stb,
                         const float* __restrict__ wbuf, int l, const TIN* __restrict__ emb_in,
                         TOUT* __restrict__ emb_out) {
  __shared__ float sab[80];
  int tid = threadIdx.x;
  int lane = tid & 63;
  int w = tid >> 6;
  int r = blockIdx.x * 4 + w;
  int hh = lane >> 3;
  if (tid < 80) {
    float a = wbuf[W_ABIN + l * 80 + tid];
    sab[tid] = (a > 0.f) ? a : 0.2f * a;
  }
  __syncthreads();
  const float* pwt = wbuf + W_APW + l * 8192;
  const float* pwb = pwt + 4096;
  const float* aw = wbuf + W_AW + l * 4096;
  const float* rw = wbuf + W_RW + l * 4096;

  float ev = ldv(emb_in, (size_t)r * 64 + lane);
  float xh = wbuf[W_APB + l * 64 + lane];
  float res = wbuf[W_RB + l * 64 + lane];
  for (int i = 0; i < 64; i++) {
    float e = __shfl(ev, i);
    xh = fmaf(e, pwt[i * 64 + lane], xh);
    res = fmaf(e, rw[i * 64 + lane], res);
  }
  res = fmaxf(res, 0.f);
  float av = wbuf[W_AVEC + l * 64 + lane];
  float abl = wbuf[W_AB + l * 64 + lane];

  int beg = (r == 0) ? 0 : row_ptr[r - 1];
  int end = row_ptr[r];
  float num = 0.f, den = 0.f;
  for (int j = beg; j < end; j++) {
    int p = stb[j];
    int t = p & 0xFFFF;
    float tv = ldv(emb_in, (size_t)t * 64 + lane);
    float z = xh + dotcol(pwb, tv, lane);
    z = (z > 0.f) ? z : 0.2f * z;
    float v = z * av;
    v += __shfl_xor(v, 1);
    v += __shfl_xor(v, 2);
    v += __shfl_xor(v, 4);
    float e = __expf(v + sab[(p >> 16) * 8 + hh]);
    den += e;
    float mt = dotcol(aw, tv, lane) + abl;
    num = fmaf(mt, e, num);
  }
  stv(emb_out, (size_t)r * 64 + lane, fmaxf(num / (den + 1e-16f), 0.f) + res);
}

// ---------------- launch ----------------

extern "C" void kernel_launch(void* const* d_in, const int* in_sizes, int n_in,
                              void* d_out, int out_size, void* d_ws, size_t ws_size,
                              hipStream_t stream) {
  const unsigned int* trip_w = (const unsigned int*)d_in[0];
  const void* rel_emb = d_in[1];
  float* emb = (float*)d_out;

  char* ws = (char*)d_ws;
  int* flag = (int*)(ws + O_FLAG);
  float* wbuf = (float*)(ws + O_WBUF);
  int* row_ptr = (int*)(ws + O_ROWP);
  int* counts = (int*)(ws + O_CNTS);
  int* partial = (int*)(ws + O_PART);
  int* stb = (int*)(ws + O_STB);
  char* big = ws + O_BIG;

  k_detect_init<<<160, 256, 0, stream>>>(trip_w, (const unsigned short*)rel_emb, flag, counts,
                                         stb, partial);
  int eb_blocks = (E_NUM + 255) / 256;
  k_hist_wconv<<<WCONV_BLOCKS + eb_blocks, 256, 0, stream>>>(
      trip_w, flag, counts, d_in[2], d_in[3], d_in[4], d_in[5], d_in[6], d_in[7], d_in[8],
      d_in[9], d_in[10], d_in[11], wbuf);
  k_scan1<<<40, 1024, 0, stream>>>(counts, partial, row_ptr);
  k_scatter<<<eb_blocks, 256, 0, stream>>>(trip_w, flag, row_ptr, stb);

  if (ws_size >= NEED_LEAN) {
    unsigned int* XMp = (unsigned int*)big;
    float2* HR = (float2*)(big + XMP_BYTES);
    k_emb0xm_p<<<R_NUM / 32, 256, 0, stream>>>(rel_emb, flag, wbuf, emb, XMp, HR);
    k_edge_lean<<<R_NUM / 4, 256, 0, stream>>>(row_ptr, stb, XMp, HR, wbuf, 0, emb);
    k_xmhr_p<<<R_NUM / 32, 256, 0, stream>>>(emb, wbuf, 1, XMp, HR);
    k_edge_lean<<<R_NUM / 4, 256, 0, stream>>>(row_ptr, stb, XMp, HR, wbuf, 1, emb);
  } else if (ws_size >= NEED_XM1) {
    float2* XM = (float2*)big;
    k_emb0<<<R_NUM / 16, 256, 0, stream>>>(rel_emb, flag, wbuf, emb);
    k_xm<<<R_NUM / 16, 256, 0, stream>>>(emb, wbuf, 0, XM);
    k_edge_f<<<R_NUM / 16, 256, 0, stream>>>(row_ptr, stb, XM, wbuf, 0, emb);
    k_xm<<<R_NUM / 16, 256, 0, stream>>>(emb, wbuf, 1, XM);
    k_edge_f<<<R_NUM / 16, 256, 0, stream>>>(row_ptr, stb, XM, wbuf, 1, emb);
  } else {
    k_emb0<<<R_NUM / 16, 256, 0, stream>>>(rel_emb, flag, wbuf, emb);
    bf16* embB = (bf16*)big;
    k_edge_d<float, bf16><<<R_NUM / 4, 256, 0, stream>>>(row_ptr, stb, wbuf, 0, emb, embB);
    k_edge_d<bf16, float><<<R_NUM / 4, 256, 0, stream>>>(row_ptr, stb, wbuf, 1, embB, emb);
  }
}